// Round 5
// baseline (280.389 us; speedup 1.0000x reference)
//
#include <hip/hip_runtime.h>
#include <stdint.h>
#include <math.h>

// cdist-attention, bf16 MFMA pipeline. R5: 256x256 GEMM, BK=32 double-buffer
// (LDS 64 KiB -> 2 blocks/CU co-resident; R4's 128 KiB forced 1 block/CU and
// all pipes <25% busy = latency-bound lockstep). 2-phase/tile schedule:
//   P1: ds_read aF(4)+b(4), stage tile t+1 (4 glds), barrier, lgkm0, 16 MFMA
//   P2: ds_read aH(4), barrier, lgkm0, 16 MFMA, vmcnt(0), barrier
// Swizzle: stored chunk = kq ^ ((row>>1)&3) -> each 8-lane b128 subgroup hits
// all 8 16B slots once (conflict-free); staging pre-swizzles the GLOBAL source
// so LDS dst stays linear (global_load_lds requirement).

typedef __attribute__((ext_vector_type(8))) __bf16 bf16x8;
typedef __attribute__((ext_vector_type(4))) float f32x4;

__device__ __forceinline__ unsigned short f2b(float f) {
    unsigned u = __float_as_uint(f);
    unsigned r = 0x7fffu + ((u >> 16) & 1u);
    return (unsigned short)((u + r) >> 16);
}
__device__ __forceinline__ float b2f(unsigned short h) {
    return __uint_as_float(((unsigned)h) << 16);
}

__device__ __forceinline__ void wg_barrier() {
    asm volatile("" ::: "memory");
    __builtin_amdgcn_s_barrier();
    asm volatile("" ::: "memory");
}

__device__ __forceinline__ void glds16(const unsigned short* src, unsigned short* dst) {
    __builtin_amdgcn_global_load_lds(
        (const __attribute__((address_space(1))) unsigned int*)src,
        (__attribute__((address_space(3))) unsigned int*)dst, 16, 0, 0);
}

__device__ __forceinline__ unsigned lds_off(const void* p) {
    return (unsigned)(uintptr_t)(const __attribute__((address_space(3))) char*)p;
}

__global__ __launch_bounds__(256) void castk(const float* __restrict__ src,
                                             unsigned short* __restrict__ dst, int n4) {
    int i = blockIdx.x * 256 + threadIdx.x;
    if (i >= n4) return;
    float4 v = ((const float4*)src)[i];
    ushort4 o;
    o.x = f2b(v.x); o.y = f2b(v.y); o.z = f2b(v.z); o.w = f2b(v.w);
    ((ushort4*)dst)[i] = o;
}

// MODE 0: row sum; MODE 1: row sum of squares. One wave per row.
template <int MODE>
__global__ __launch_bounds__(256) void rowreduce(const unsigned short* __restrict__ X,
                                                 int L, int rows, float* __restrict__ out) {
    int w = threadIdx.x >> 6, lane = threadIdx.x & 63;
    int row = blockIdx.x * 4 + w;
    if (row >= rows) return;
    const unsigned short* xr = X + (size_t)row * L;
    float s = 0.f;
    int passes = L >> 8;
    for (int p = 0; p < passes; ++p) {
        ushort4 u = *(const ushort4*)(xr + (p << 8) + lane * 4);
        float a = b2f(u.x), b = b2f(u.y), c = b2f(u.z), d = b2f(u.w);
        s += MODE ? (a * a + b * b + c * c + d * d) : (a + b + c + d);
    }
#pragma unroll
    for (int o = 32; o > 0; o >>= 1) s += __shfl_down(s, o);
    if (lane == 0) out[row] = s;
}

#define MF(A_, B_, C_) (C_) = __builtin_amdgcn_mfma_f32_16x16x32_bf16((A_), (B_), (C_), 0, 0, 0)
#define DSR(dst_, a_, imm_) \
    asm volatile("ds_read_b128 %0, %1 offset:" #imm_ : "=v"(dst_) : "v"(a_))
#define LGKM0 asm volatile("s_waitcnt lgkmcnt(0)" ::: "memory")
#define VMC0 asm volatile("s_waitcnt vmcnt(0)" ::: "memory")
#define SB0 __builtin_amdgcn_sched_barrier(0)

// stage tile T (k0 = T*32) into LDS buffer BUFW (0/1): 2 chunks per operand.
#define SA_(T_, BUFW_) do {                                                \
    const unsigned short* s_ = pA0 + (size_t)(T_) * 32;                    \
    unsigned short* d_ = As + (BUFW_) * 8192 + tid * 8;                    \
    glds16(s_, d_);                                                        \
    glds16(s_ + (size_t)128 * lda, d_ + 4096);                             \
} while (0)
#define SB_(T_, BUFW_) do {                                                \
    const unsigned short* s_ = pB0 + (size_t)(T_) * 32;                    \
    unsigned short* d_ = Bs + (BUFW_) * 8192 + tid * 8;                    \
    glds16(s_, d_);                                                        \
    glds16(s_ + (size_t)128 * ldb, d_ + 4096);                             \
} while (0)

// One K-tile (BK=32): 2 phases of 16 MFMA.
#define TILE(AD_, BD_, T_, BUFW_) do {                                     \
    bf16x8 af[4], ah[4], bv[4];                                            \
    DSR(af[0], AD_, 0);    DSR(af[1], AD_, 1024);                          \
    DSR(af[2], AD_, 2048); DSR(af[3], AD_, 3072);                          \
    DSR(bv[0], BD_, 0);    DSR(bv[1], BD_, 1024);                          \
    DSR(bv[2], BD_, 2048); DSR(bv[3], BD_, 3072);                          \
    if ((T_) + 1 < nt) { SA_((T_) + 1, BUFW_); SB_((T_) + 1, BUFW_); }     \
    wg_barrier();                                                          \
    LGKM0; SB0;                                                            \
    __builtin_amdgcn_s_setprio(1);                                         \
    _Pragma("unroll") for (int mi_ = 0; mi_ < 4; ++mi_)                    \
        _Pragma("unroll") for (int ni_ = 0; ni_ < 4; ++ni_)                \
            MF(af[mi_], bv[ni_], acc[mi_][ni_]);                           \
    SB0; __builtin_amdgcn_s_setprio(0);                                    \
    wg_barrier();                                                          \
    DSR(ah[0], AD_, 4096); DSR(ah[1], AD_, 5120);                          \
    DSR(ah[2], AD_, 6144); DSR(ah[3], AD_, 7168);                          \
    wg_barrier();                                                          \
    LGKM0; SB0;                                                            \
    __builtin_amdgcn_s_setprio(1);                                         \
    _Pragma("unroll") for (int mi_ = 0; mi_ < 4; ++mi_)                    \
        _Pragma("unroll") for (int ni_ = 0; ni_ < 4; ++ni_)                \
            MF(ah[mi_], bv[ni_], acc[4 + mi_][ni_]);                       \
    SB0; __builtin_amdgcn_s_setprio(0);                                    \
    VMC0;                                                                  \
    wg_barrier();                                                          \
} while (0)

// C[m][n] = sum_k A[m][k]*B[n][k].
// EPI 0: store bf16.  EPI 1: scores epilogue.  EPI 2: store f32 = acc/aux1[row].
template <int EPI>
__global__ __launch_bounds__(512, 2) void gemm256(
    const unsigned short* __restrict__ A, int lda, long long sA,
    const unsigned short* __restrict__ B, int ldb, long long sB,
    void* __restrict__ Cv, int ldc, long long sC,
    int Kd,
    const float* __restrict__ aux1, int sAux1,
    const float* __restrict__ aux2, int sAux2,
    float invs) {
    // [2 buf][256 rows][4 chunks of 16B] = 16 KiB per buf per operand = 64 KiB
    __shared__ __attribute__((aligned(128))) unsigned short As[2 * 256 * 32];
    __shared__ __attribute__((aligned(128))) unsigned short Bs[2 * 256 * 32];

    const int z = blockIdx.z;
    const unsigned short* __restrict__ Ab = A + (size_t)z * sA;
    const unsigned short* __restrict__ Bb = B + (size_t)z * sB;
    const int i0 = blockIdx.y * 256;
    const int j0 = blockIdx.x * 256;
    const int tid = threadIdx.x;
    const int w = tid >> 6, lane = tid & 63;
    const int wr = w >> 2, wc = w & 3;          // 2 x 4 wave grid
    const int c16 = lane & 15, kq = lane >> 4;  // frag col / k-octet

    // staging source (pre-swizzled global chunk; LDS dst linear).
    // LDS chunk f = tid (+512): ldsrow = f>>2, c_store = f&3,
    // c_log = c_store ^ ((ldsrow>>1)&3) = (tid&3) ^ ((tid>>3)&3).
    const int srow = tid >> 2;
    const int clog = (tid & 3) ^ ((tid >> 3) & 3);
    const unsigned short* pA0 = Ab + (size_t)(i0 + srow) * lda + clog * 8;
    const unsigned short* pB0 = Bb + (size_t)(j0 + srow) * ldb + clog * 8;

    // frag read bases: byte = row*64 + ((kq ^ ((row>>1)&3))<<4); row = 16m + c16
    // -> (row>>1)&3 == (c16>>1)&3, so one base + offset:mi*1024.
    const int swc = (kq ^ ((c16 >> 1) & 3)) << 4;
    const unsigned adrA0 = lds_off(As) + (unsigned)(wr * 128 + c16) * 64 + swc;
    const unsigned adrA1 = adrA0 + 16384u;
    const unsigned adrB0 = lds_off(Bs) + (unsigned)(wc * 64 + c16) * 64 + swc;
    const unsigned adrB1 = adrB0 + 16384u;

    f32x4 acc[8][4];
    const f32x4 zero = {0.f, 0.f, 0.f, 0.f};
#pragma unroll
    for (int i = 0; i < 8; ++i)
#pragma unroll
        for (int j = 0; j < 4; ++j) acc[i][j] = zero;

    const int nt = Kd >> 5;  // K-tiles of 32; requires Kd % 64 == 0

    // prologue: stage tile 0 into buf0; drain; barrier
    SA_(0, 0); SB_(0, 0);
    VMC0;
    wg_barrier();

    for (int t = 0; t < nt; t += 2) {
        TILE(adrA0, adrB0, t, 1);      // compute buf0, stage t+1 -> buf1
        TILE(adrA1, adrB1, t + 1, 0);  // compute buf1, stage t+2 -> buf0
    }

    // C/D layout: col = lane&15, row = (lane>>4)*4 + reg
    const int r4 = kq * 4;
    if constexpr (EPI == 0) {
        unsigned short* C = (unsigned short*)Cv + (size_t)z * sC;
#pragma unroll
        for (int mi = 0; mi < 8; ++mi)
#pragma unroll
            for (int ni = 0; ni < 4; ++ni) {
                const int row = i0 + wr * 128 + mi * 16 + r4;
                const int col = j0 + wc * 64 + ni * 16 + c16;
#pragma unroll
                for (int r = 0; r < 4; ++r)
                    C[(size_t)(row + r) * ldc + col] = f2b(acc[mi][ni][r]);
            }
    } else if constexpr (EPI == 1) {
        unsigned short* C = (unsigned short*)Cv + (size_t)z * sC;
        const float* q2b = aux1 + (size_t)z * sAux1;
        const float* k2b = aux2 + (size_t)z * sAux2;
#pragma unroll
        for (int mi = 0; mi < 8; ++mi)
#pragma unroll
            for (int ni = 0; ni < 4; ++ni) {
                const int row = i0 + wr * 128 + mi * 16 + r4;
                const int col = j0 + wc * 64 + ni * 16 + c16;
                const float k2v = k2b[col];
#pragma unroll
                for (int r = 0; r < 4; ++r) {
                    float d2 = q2b[row + r] + k2v - 2.0f * acc[mi][ni][r];
                    float e = __expf(sqrtf(fmaxf(d2, 0.f)) * invs);
                    C[(size_t)(row + r) * ldc + col] = f2b(e);
                }
            }
    } else {
        float* C = (float*)Cv + (size_t)z * sC;
        const float* lb = aux1 + (size_t)z * sAux1;
#pragma unroll
        for (int mi = 0; mi < 8; ++mi)
#pragma unroll
            for (int ni = 0; ni < 4; ++ni) {
                const int row = i0 + wr * 128 + mi * 16 + r4;
                const int col = j0 + wc * 64 + ni * 16 + c16;
#pragma unroll
                for (int r = 0; r < 4; ++r)
                    C[(size_t)(row + r) * ldc + col] = acc[mi][ni][r] / lb[row + r];
            }
    }
}

extern "C" void kernel_launch(void* const* d_in, const int* in_sizes, int n_in,
                              void* d_out, int out_size, void* d_ws, size_t ws_size,
                              hipStream_t stream) {
    const float* x = (const float*)d_in[0];
    const float* Wq = (const float*)d_in[1];
    const float* Wk = (const float*)d_in[2];
    const float* Wv = (const float*)d_in[3];
    const int Bz = 8, S = 2048, D = 768, F = 768;
    const int BS = Bz * S;  // 16384

    const size_t szX = (size_t)BS * D * 2;
    const size_t szW = (size_t)F * D * 2;
    const size_t szE = (size_t)Bz * S * S * 2;

    char* p = (char*)d_ws;
    unsigned short* xb = (unsigned short*)p;  p += szX;
    unsigned short* Wqb = (unsigned short*)p; p += szW;
    unsigned short* Wkb = (unsigned short*)p; p += szW;
    unsigned short* Wvb = (unsigned short*)p; p += szW;
    unsigned short* Qm = (unsigned short*)p;  p += szX;
    unsigned short* Km = (unsigned short*)p;  p += szX;
    unsigned short* VT = (unsigned short*)p;  p += szX;  // [F][BS]
    unsigned short* E = (unsigned short*)p;   p += szE;  // [Bz][S][S]
    float* q2 = (float*)p;   p += (size_t)BS * 4;
    float* k2 = (float*)p;   p += (size_t)BS * 4;
    float* lsum = (float*)p; p += (size_t)BS * 4;
    if ((size_t)(p - (char*)d_ws) > ws_size) return;  // ~164 MiB scratch required

    const float invs = 1.0f / sqrtf(768.0f);

    // 1) casts
    castk<<<(BS * D / 4 + 255) / 256, 256, 0, stream>>>(x, xb, BS * D / 4);
    castk<<<(F * D / 4 + 255) / 256, 256, 0, stream>>>(Wq, Wqb, F * D / 4);
    castk<<<(F * D / 4 + 255) / 256, 256, 0, stream>>>(Wk, Wkb, F * D / 4);
    castk<<<(F * D / 4 + 255) / 256, 256, 0, stream>>>(Wv, Wvb, F * D / 4);

    // 2) Q,K = x . W^T  (z=0 -> Wq, z=1 -> Wk)
    gemm256<0><<<dim3(F / 256, BS / 256, 2), 512, 0, stream>>>(
        xb, D, 0,
        Wqb, D, (long long)F * D,
        Qm, F, (long long)BS * F,
        D, nullptr, 0, nullptr, 0, 0.f);

    //    V^T = Wv . x^T   -> VT[f][s]
    gemm256<0><<<dim3(BS / 256, F / 256, 1), 512, 0, stream>>>(
        Wvb, D, 0,
        xb, D, 0,
        VT, BS, 0,
        D, nullptr, 0, nullptr, 0, 0.f);

    // 3) row norms of Q,K
    rowreduce<1><<<BS / 4, 256, 0, stream>>>(Qm, F, BS, q2);
    rowreduce<1><<<BS / 4, 256, 0, stream>>>(Km, F, BS, k2);

    // 4) E = exp(sqrt(max(q2+k2-2*Q.K^T,0))*invs)
    gemm256<1><<<dim3(S / 256, S / 256, Bz), 512, 0, stream>>>(
        Qm, F, (long long)S * F,
        Km, F, (long long)S * F,
        E, S, (long long)S * S,
        F, q2, S, k2, S, invs);

    // 5) l = rowsum(E)
    rowreduce<0><<<BS / 4, 256, 0, stream>>>(E, S, BS, lsum);

    // 6) out = (E . V) / l
    gemm256<2><<<dim3(F / 256, S / 256, Bz), 512, 0, stream>>>(
        E, S, (long long)S * S,
        VT, BS, (long long)S,
        d_out, F, (long long)S * F,
        S, lsum, S, nullptr, 0, 0.f);
}

// Round 6
// 244.410 us; speedup vs baseline: 1.1472x; 1.1472x over previous
//
#include <hip/hip_runtime.h>
#include <stdint.h>
#include <math.h>

// cdist-attention, bf16 MFMA pipeline, m201-style 8-phase 256x256 GEMM.
// R6: XCD-batch locality. Dispatch analysis showed scores GEMM at 6.1k
// cyc/K-tile vs 2.2-2.7k for QK/VT/PV (same kernel!): scores' staging
// working set per XCD = Q,K for ALL batches (48 MB >> 4 MB L2) because
// blocks round-robin over XCDs. FETCH=111MB vs ~50 compulsory = HBM
// re-fetch; staging delivery ~2k cyc/tile was the wall.
// Fix: grid perm so blockIdx.x == z -> XCD i owns batch i (round-robin
// wg->XCD): per-XCD set = K_z(3MB)+A-panel(0.4MB) < 4MB L2. PV likewise
// (and reads E_z dirty in the same XCD's L2 that scores wrote it from).

typedef __attribute__((ext_vector_type(8))) __bf16 bf16x8;
typedef __attribute__((ext_vector_type(4))) float f32x4;

__device__ __forceinline__ unsigned short f2b(float f) {
    unsigned u = __float_as_uint(f);
    unsigned r = 0x7fffu + ((u >> 16) & 1u);
    return (unsigned short)((u + r) >> 16);
}
__device__ __forceinline__ float b2f(unsigned short h) {
    return __uint_as_float(((unsigned)h) << 16);
}

__device__ __forceinline__ void wg_barrier() {
    asm volatile("" ::: "memory");
    __builtin_amdgcn_s_barrier();
    asm volatile("" ::: "memory");
}

__device__ __forceinline__ void glds16(const unsigned short* src, unsigned short* dst) {
    __builtin_amdgcn_global_load_lds(
        (const __attribute__((address_space(1))) unsigned int*)src,
        (__attribute__((address_space(3))) unsigned int*)dst, 16, 0, 0);
}

__device__ __forceinline__ unsigned lds_off(const void* p) {
    return (unsigned)(uintptr_t)(const __attribute__((address_space(3))) char*)p;
}

__global__ __launch_bounds__(256) void castk(const float* __restrict__ src,
                                             unsigned short* __restrict__ dst, int n4) {
    int i = blockIdx.x * 256 + threadIdx.x;
    if (i >= n4) return;
    float4 v = ((const float4*)src)[i];
    ushort4 o;
    o.x = f2b(v.x); o.y = f2b(v.y); o.z = f2b(v.z); o.w = f2b(v.w);
    ((ushort4*)dst)[i] = o;
}

// MODE 0: row sum; MODE 1: row sum of squares. One wave per row.
template <int MODE>
__global__ __launch_bounds__(256) void rowreduce(const unsigned short* __restrict__ X,
                                                 int L, int rows, float* __restrict__ out) {
    int w = threadIdx.x >> 6, lane = threadIdx.x & 63;
    int row = blockIdx.x * 4 + w;
    if (row >= rows) return;
    const unsigned short* xr = X + (size_t)row * L;
    float s = 0.f;
    int passes = L >> 8;
    for (int p = 0; p < passes; ++p) {
        ushort4 u = *(const ushort4*)(xr + (p << 8) + lane * 4);
        float a = b2f(u.x), b = b2f(u.y), c = b2f(u.z), d = b2f(u.w);
        s += MODE ? (a * a + b * b + c * c + d * d) : (a + b + c + d);
    }
#pragma unroll
    for (int o = 32; o > 0; o >>= 1) s += __shfl_down(s, o);
    if (lane == 0) out[row] = s;
}

#define MF(A_, B_, C_) (C_) = __builtin_amdgcn_mfma_f32_16x16x32_bf16((A_), (B_), (C_), 0, 0, 0)
#define DSR(dst_, a_, imm_) \
    asm volatile("ds_read_b128 %0, %1 offset:" #imm_ : "=v"(dst_) : "v"(a_))
#define LGKM(n_) asm volatile("s_waitcnt lgkmcnt(" #n_ ")" ::: "memory")
#define VMC6 asm volatile("s_waitcnt vmcnt(6)" ::: "memory")
#define VMC0 asm volatile("s_waitcnt vmcnt(0)" ::: "memory")
#define SB0 __builtin_amdgcn_sched_barrier(0)
#define NOPS ((void)0)

#define CLUSTER(MI0_, NI0_, AARR_, BARR_)                                  \
    _Pragma("unroll") for (int mi_ = 0; mi_ < 4; ++mi_) {                  \
        _Pragma("unroll") for (int ni_ = 0; ni_ < 2; ++ni_) {              \
            MF(AARR_[mi_][0], BARR_[ni_][0], acc[(MI0_) + mi_][(NI0_) + ni_]); \
            MF(AARR_[mi_][1], BARR_[ni_][1], acc[(MI0_) + mi_][(NI0_) + ni_]); \
        }                                                                  \
    }

// One K-tile = 4 phases. S1..S4 are staging statements; VMW_ the boundary wait.
#define TILE(A0_, A0X_, B0_, B0X_, S1_, S2_, S3_, S4_, VMW_) do {          \
    DSR(aF[0][0], A0_, 0);    DSR(aF[0][1], A0X_, 0);                      \
    DSR(aF[1][0], A0_, 2048); DSR(aF[1][1], A0X_, 2048);                   \
    DSR(aF[2][0], A0_, 4096); DSR(aF[2][1], A0X_, 4096);                   \
    DSR(aF[3][0], A0_, 6144); DSR(aF[3][1], A0X_, 6144);                   \
    DSR(bL[0][0], B0_, 0);    DSR(bL[0][1], B0X_, 0);                      \
    DSR(bL[1][0], B0_, 2048); DSR(bL[1][1], B0X_, 2048);                   \
    S1_;                                                                   \
    LGKM(8);                                                               \
    wg_barrier();                                                          \
    LGKM(0); SB0;                                                          \
    __builtin_amdgcn_s_setprio(1);                                         \
    CLUSTER(0, 0, aF, bL)                                                  \
    SB0; __builtin_amdgcn_s_setprio(0);                                    \
    wg_barrier();                                                          \
    DSR(bH[0][0], B0_, 4096); DSR(bH[0][1], B0X_, 4096);                   \
    DSR(bH[1][0], B0_, 6144); DSR(bH[1][1], B0X_, 6144);                   \
    S2_;                                                                   \
    wg_barrier();                                                          \
    LGKM(0); SB0;                                                          \
    __builtin_amdgcn_s_setprio(1);                                         \
    CLUSTER(0, 2, aF, bH)                                                  \
    SB0; __builtin_amdgcn_s_setprio(0);                                    \
    wg_barrier();                                                          \
    DSR(aH[0][0], A0_, 8192);  DSR(aH[0][1], A0X_, 8192);                  \
    DSR(aH[1][0], A0_, 10240); DSR(aH[1][1], A0X_, 10240);                 \
    DSR(aH[2][0], A0_, 12288); DSR(aH[2][1], A0X_, 12288);                 \
    DSR(aH[3][0], A0_, 14336); DSR(aH[3][1], A0X_, 14336);                 \
    S3_;                                                                   \
    wg_barrier();                                                          \
    LGKM(0); SB0;                                                          \
    __builtin_amdgcn_s_setprio(1);                                         \
    CLUSTER(4, 2, aH, bH)                                                  \
    SB0; __builtin_amdgcn_s_setprio(0);                                    \
    wg_barrier();                                                          \
    S4_;                                                                   \
    VMW_;                                                                  \
    wg_barrier();                                                          \
    SB0;                                                                   \
    __builtin_amdgcn_s_setprio(1);                                         \
    CLUSTER(4, 0, aH, bL)                                                  \
    SB0; __builtin_amdgcn_s_setprio(0);                                    \
    wg_barrier();                                                          \
} while (0)

// Stage A-half H of K-tile T into buffer BUF (64-row interleave).
#define SA_(T_, BUF_, H_) do {                                             \
    const unsigned short* s_ = pA0 + (size_t)((H_) * 64) * lda + (size_t)(T_) * 64; \
    unsigned short* d_ = As + (BUF_) * 16384 + (H_) * 4096 + tid * 8;      \
    glds16(s_, d_);                                                        \
    glds16(s_ + (size_t)128 * lda, d_ + 8192);                             \
} while (0)
// Stage B-half H (32-row interleave).
#define SBs_(T_, BUF_, H_) do {                                            \
    const unsigned short* s_ = pB0 + (size_t)((H_) * 32) * ldb + (size_t)(T_) * 64; \
    unsigned short* d_ = Bs + (BUF_) * 16384 + (H_) * 2048 + dB0 + tid * 8; \
    glds16(s_, d_);                                                        \
    glds16(s_ + (size_t)128 * ldb, d_ + 8192);                             \
} while (0)

// C[m][n] = sum_k A[m][k]*B[n][k].
// perm=0: (x=colTile, y=rowTile, z=batch). perm=1: (x=batch, y=colTile,
// z=rowTile) -> round-robin wg->XCD gives XCD i all blocks of batch i.
// EPI 0: store bf16.  EPI 1: scores epilogue.  EPI 2: store f32 = acc/aux1[row].
template <int EPI>
__global__ __launch_bounds__(512, 2) void gemm256(
    const unsigned short* __restrict__ A, int lda, long long sA,
    const unsigned short* __restrict__ B, int ldb, long long sB,
    void* __restrict__ Cv, int ldc, long long sC,
    int Kd, int perm,
    const float* __restrict__ aux1, int sAux1,
    const float* __restrict__ aux2, int sAux2,
    float invs) {
    __shared__ __attribute__((aligned(128))) unsigned short As[2 * 256 * 64];
    __shared__ __attribute__((aligned(128))) unsigned short Bs[2 * 256 * 64];

    const int z = perm ? blockIdx.x : blockIdx.z;
    const int jb = perm ? blockIdx.y : blockIdx.x;
    const int ib = perm ? blockIdx.z : blockIdx.y;
    const unsigned short* __restrict__ Ab = A + (size_t)z * sA;
    const unsigned short* __restrict__ Bb = B + (size_t)z * sB;
    const int i0 = ib * 256;
    const int j0 = jb * 256;
    const int tid = threadIdx.x;
    const int w = tid >> 6, lane = tid & 63;
    const int wr = w >> 2, wc = w & 3;          // 2 x 4 wave grid
    const int c16 = lane & 15, kq = lane >> 4;  // frag col / k-octet

    // staging source (pre-swizzled global chunk; LDS dst stays linear)
    const int lr0 = tid >> 3;                    // 0..63
    const int clog0 = (tid & 7) ^ (lr0 & 7);     // logical 16B chunk
    const unsigned short* pA0 = Ab + (size_t)(i0 + lr0) * lda + clog0 * 8;
    const unsigned short* pB0 = Bb + (size_t)(j0 + lr0 + (lr0 & 32)) * ldb + clog0 * 8;
    const int dB0 = (tid & 256) << 3;  // +2048 shorts for tid>=256 (row group +64)

    // frag read bases (swizzled): stored chunk = (kk*4+kq) ^ (row&7); row&7==c16&7
    const int swc = (kq ^ (c16 & 7)) << 4;
    const unsigned adrA0 = lds_off(As) + (unsigned)(wr * 128 + c16) * 128 + swc;
    const unsigned adrA0x = adrA0 ^ 64u;
    const unsigned adrA1 = adrA0 + 32768u, adrA1x = adrA0x + 32768u;
    const unsigned adrB0 = lds_off(Bs) + (unsigned)(wc * 64 + c16) * 128 + swc;
    const unsigned adrB0x = adrB0 ^ 64u;
    const unsigned adrB1 = adrB0 + 32768u, adrB1x = adrB0x + 32768u;

    f32x4 acc[8][4];
    const f32x4 zero = {0.f, 0.f, 0.f, 0.f};
#pragma unroll
    for (int i = 0; i < 8; ++i)
#pragma unroll
        for (int j = 0; j < 4; ++j) acc[i][j] = zero;

    bf16x8 aF[4][2], aH[4][2], bL[2][2], bH[2][2];

    const int npairs = Kd >> 7;  // BK=64 tile pairs; requires Kd % 128 == 0, >= 2

    // prologue: tile0 all 4 halves (buf0); tile1 Ah0,Bh0,Ah1 (buf1); vmcnt(6)
    SA_(0, 0, 0); SA_(0, 0, 1); SBs_(0, 0, 0); SBs_(0, 0, 1);
    SA_(1, 1, 0); SBs_(1, 1, 0); SA_(1, 1, 1);
    VMC6;
    wg_barrier();

    for (int u = 0; u < npairs - 1; ++u) {
        const int t0 = 2 * u;
        TILE(adrA0, adrA0x, adrB0, adrB0x,
             SBs_(t0 + 1, 1, 1), SA_(t0 + 2, 0, 0), SBs_(t0 + 2, 0, 0), SA_(t0 + 2, 0, 1),
             VMC6);
        TILE(adrA1, adrA1x, adrB1, adrB1x,
             SBs_(t0 + 2, 0, 1), SA_(t0 + 3, 1, 0), SBs_(t0 + 3, 1, 0), SA_(t0 + 3, 1, 1),
             VMC6);
    }
    {   // tail pair: finish Bh1(last tile); drain; last tile pure compute
        const int t0 = 2 * npairs - 2;
        TILE(adrA0, adrA0x, adrB0, adrB0x,
             SBs_(t0 + 1, 1, 1), NOPS, NOPS, NOPS, VMC0);
        TILE(adrA1, adrA1x, adrB1, adrB1x, NOPS, NOPS, NOPS, NOPS, NOPS);
    }

    // C/D layout: col = lane&15, row = (lane>>4)*4 + reg
    const int r4 = kq * 4;
    if constexpr (EPI == 0) {
        unsigned short* C = (unsigned short*)Cv + (size_t)z * sC;
#pragma unroll
        for (int mi = 0; mi < 8; ++mi)
#pragma unroll
            for (int ni = 0; ni < 4; ++ni) {
                const int row = i0 + wr * 128 + mi * 16 + r4;
                const int col = j0 + wc * 64 + ni * 16 + c16;
#pragma unroll
                for (int r = 0; r < 4; ++r)
                    C[(size_t)(row + r) * ldc + col] = f2b(acc[mi][ni][r]);
            }
    } else if constexpr (EPI == 1) {
        unsigned short* C = (unsigned short*)Cv + (size_t)z * sC;
        const float* q2b = aux1 + (size_t)z * sAux1;
        const float* k2b = aux2 + (size_t)z * sAux2;
#pragma unroll
        for (int mi = 0; mi < 8; ++mi)
#pragma unroll
            for (int ni = 0; ni < 4; ++ni) {
                const int row = i0 + wr * 128 + mi * 16 + r4;
                const int col = j0 + wc * 64 + ni * 16 + c16;
                const float k2v = k2b[col];
#pragma unroll
                for (int r = 0; r < 4; ++r) {
                    float d2 = q2b[row + r] + k2v - 2.0f * acc[mi][ni][r];
                    float e = __expf(sqrtf(fmaxf(d2, 0.f)) * invs);
                    C[(size_t)(row + r) * ldc + col] = f2b(e);
                }
            }
    } else {
        float* C = (float*)Cv + (size_t)z * sC;
        const float* lb = aux1 + (size_t)z * sAux1;
#pragma unroll
        for (int mi = 0; mi < 8; ++mi)
#pragma unroll
            for (int ni = 0; ni < 4; ++ni) {
                const int row = i0 + wr * 128 + mi * 16 + r4;
                const int col = j0 + wc * 64 + ni * 16 + c16;
#pragma unroll
                for (int r = 0; r < 4; ++r)
                    C[(size_t)(row + r) * ldc + col] = acc[mi][ni][r] / lb[row + r];
            }
    }
}

extern "C" void kernel_launch(void* const* d_in, const int* in_sizes, int n_in,
                              void* d_out, int out_size, void* d_ws, size_t ws_size,
                              hipStream_t stream) {
    const float* x = (const float*)d_in[0];
    const float* Wq = (const float*)d_in[1];
    const float* Wk = (const float*)d_in[2];
    const float* Wv = (const float*)d_in[3];
    const int Bz = 8, S = 2048, D = 768, F = 768;
    const int BS = Bz * S;  // 16384

    const size_t szX = (size_t)BS * D * 2;
    const size_t szW = (size_t)F * D * 2;
    const size_t szE = (size_t)Bz * S * S * 2;

    char* p = (char*)d_ws;
    unsigned short* xb = (unsigned short*)p;  p += szX;
    unsigned short* Wqb = (unsigned short*)p; p += szW;
    unsigned short* Wkb = (unsigned short*)p; p += szW;
    unsigned short* Wvb = (unsigned short*)p; p += szW;
    unsigned short* Qm = (unsigned short*)p;  p += szX;
    unsigned short* Km = (unsigned short*)p;  p += szX;
    unsigned short* VT = (unsigned short*)p;  p += szX;  // [F][BS]
    unsigned short* E = (unsigned short*)p;   p += szE;  // [Bz][S][S]
    float* q2 = (float*)p;   p += (size_t)BS * 4;
    float* k2 = (float*)p;   p += (size_t)BS * 4;
    float* lsum = (float*)p; p += (size_t)BS * 4;
    if ((size_t)(p - (char*)d_ws) > ws_size) return;  // ~164 MiB scratch required

    const float invs = 1.0f / sqrtf(768.0f);

    // 1) casts
    castk<<<(BS * D / 4 + 255) / 256, 256, 0, stream>>>(x, xb, BS * D / 4);
    castk<<<(F * D / 4 + 255) / 256, 256, 0, stream>>>(Wq, Wqb, F * D / 4);
    castk<<<(F * D / 4 + 255) / 256, 256, 0, stream>>>(Wk, Wkb, F * D / 4);
    castk<<<(F * D / 4 + 255) / 256, 256, 0, stream>>>(Wv, Wvb, F * D / 4);

    // 2) Q,K = x . W^T  (z=0 -> Wq, z=1 -> Wk); B=W is L2-resident, perm=0
    gemm256<0><<<dim3(F / 256, BS / 256, 2), 512, 0, stream>>>(
        xb, D, 0,
        Wqb, D, (long long)F * D,
        Qm, F, (long long)BS * F,
        D, 0, nullptr, 0, nullptr, 0, 0.f);

    //    V^T = Wv . x^T   -> VT[f][s]; perm=0
    gemm256<0><<<dim3(BS / 256, F / 256, 1), 512, 0, stream>>>(
        Wvb, D, 0,
        xb, D, 0,
        VT, BS, 0,
        D, 0, nullptr, 0, nullptr, 0, 0.f);

    // 3) row norms of Q,K
    rowreduce<1><<<BS / 4, 256, 0, stream>>>(Qm, F, BS, q2);
    rowreduce<1><<<BS / 4, 256, 0, stream>>>(Km, F, BS, k2);

    // 4) E = exp(sqrt(max(q2+k2-2*Q.K^T,0))*invs)
    //    perm=1: XCD i owns batch i -> K_z + A-panel fit 4MB L2
    gemm256<1><<<dim3(Bz, S / 256, S / 256), 512, 0, stream>>>(
        Qm, F, (long long)S * F,
        Km, F, (long long)S * F,
        E, S, (long long)S * S,
        F, 1, q2, S, k2, S, invs);

    // 5) l = rowsum(E)
    rowreduce<0><<<BS / 4, 256, 0, stream>>>(E, S, BS, lsum);

    // 6) out = (E . V) / l; perm=1: XCD i reads E_z it just wrote + VT_z slice
    gemm256<2><<<dim3(Bz, F / 256, S / 256), 512, 0, stream>>>(
        E, S, (long long)S * S,
        VT, BS, (long long)S,
        d_out, F, (long long)S * F,
        S, 1, lsum, S, nullptr, 0, 0.f);
}